// Round 3
// baseline (714.439 us; speedup 1.0000x reference)
//
#include <hip/hip_runtime.h>
#include <hip/hip_bf16.h>

typedef __bf16 bf16x8 __attribute__((ext_vector_type(8)));
typedef float floatx4 __attribute__((ext_vector_type(4)));

constexpr int Mdim = 16384;   // B*S
constexpr int Ndim = 3072;    // 3*D
constexpr int Kdim = 1024;    // D

static __device__ __forceinline__ bf16x8 cvt8(floatx4 lo, floatx4 hi) {
    bf16x8 r;
#pragma unroll
    for (int e = 0; e < 4; ++e) { r[e] = (__bf16)lo[e]; r[e + 4] = (__bf16)hi[e]; }
    return r;
}

// ---------------------------------------------------------------------------
// Kernel 1: out = x * W_qkv^T + b.  fp32 in/out; bf16 MFMA internally.
// 128x128 tile, BK=32, 4 waves of 64x64, mfma_f32_16x16x32_bf16.
// Staging: global fp32 vector load -> cvt bf16 in reg -> ds_write_b128.
// ---------------------------------------------------------------------------
__global__ __launch_bounds__(256, 2) void gemm_bias(
    const float* __restrict__ A,     // M x K fp32
    const float* __restrict__ Bw,    // N x K fp32 (W_qkv)
    const float* __restrict__ bias,  // N fp32
    float* __restrict__ C)           // M x N fp32
{
    constexpr int TK = 32;
    __shared__ __hip_bfloat16 As[128 * TK];
    __shared__ __hip_bfloat16 Bs[128 * TK];

    const int t    = threadIdx.x;
    const int wave = t >> 6;
    const int lane = t & 63;
    const int bx   = blockIdx.x % (Ndim / 128);   // 24 n-tiles
    const int by   = blockIdx.x / (Ndim / 128);
    const int m0   = by * 128;
    const int n0   = bx * 128;
    const int wm   = wave >> 1;                   // 2x2 wave grid, 64x64 each
    const int wn   = wave & 1;

    // staging: wave w covers tile rows 16w..16w+15 (chunk0) and +64 (chunk1);
    // lane -> row 16w+(lane>>2), col (lane&3)*8  (8 elements)
    const int srow = wave * 16 + (lane >> 2);
    const int scol = (lane & 3) * 8;

    const float* Ag0 = A  + (size_t)(m0 + srow) * Kdim + scol;
    const float* Ag1 = Ag0 + (size_t)64 * Kdim;
    const float* Bg0 = Bw + (size_t)(n0 + srow) * Kdim + scol;
    const float* Bg1 = Bg0 + (size_t)64 * Kdim;

    __hip_bfloat16* Al0 = &As[srow * TK + scol];
    __hip_bfloat16* Al1 = &As[(srow + 64) * TK + scol];
    __hip_bfloat16* Bl0 = &Bs[srow * TK + scol];
    __hip_bfloat16* Bl1 = &Bs[(srow + 64) * TK + scol];

    // MFMA A/B operand layout: free dim = lane&15, k = (lane>>4)*8 + j
    const int fm = lane & 15;
    const int fk = (lane >> 4) * 8;

    floatx4 acc[4][4];
#pragma unroll
    for (int i = 0; i < 4; ++i)
#pragma unroll
        for (int j = 0; j < 4; ++j)
            acc[i][j] = (floatx4){0.f, 0.f, 0.f, 0.f};

    for (int kt = 0; kt < Kdim; kt += TK) {
        bf16x8 a0 = cvt8(*(const floatx4*)(Ag0 + kt), *(const floatx4*)(Ag0 + kt + 4));
        bf16x8 a1 = cvt8(*(const floatx4*)(Ag1 + kt), *(const floatx4*)(Ag1 + kt + 4));
        bf16x8 b0 = cvt8(*(const floatx4*)(Bg0 + kt), *(const floatx4*)(Bg0 + kt + 4));
        bf16x8 b1 = cvt8(*(const floatx4*)(Bg1 + kt), *(const floatx4*)(Bg1 + kt + 4));
        __syncthreads();                 // prior iter's LDS reads done
        *(bf16x8*)Al0 = a0;
        *(bf16x8*)Al1 = a1;
        *(bf16x8*)Bl0 = b0;
        *(bf16x8*)Bl1 = b1;
        __syncthreads();                 // staging visible to all waves

        bf16x8 af[4], bfr[4];
#pragma unroll
        for (int i = 0; i < 4; ++i) {
            af[i]  = *(const bf16x8*)&As[(wm * 64 + i * 16 + fm) * TK + fk];
            bfr[i] = *(const bf16x8*)&Bs[(wn * 64 + i * 16 + fm) * TK + fk];
        }
#pragma unroll
        for (int i = 0; i < 4; ++i)
#pragma unroll
            for (int j = 0; j < 4; ++j)
                acc[i][j] = __builtin_amdgcn_mfma_f32_16x16x32_bf16(af[i], bfr[j], acc[i][j], 0, 0, 0);
    }

    // epilogue: C/D layout col(n)=lane&15, row(m)=(lane>>4)*4 + reg
    const int cn = lane & 15;
    const int cm = (lane >> 4) * 4;
    float bv[4];
#pragma unroll
    for (int j = 0; j < 4; ++j)
        bv[j] = bias[n0 + wn * 64 + j * 16 + cn];

#pragma unroll
    for (int i = 0; i < 4; ++i) {
        const int m = m0 + wm * 64 + i * 16 + cm;
#pragma unroll
        for (int j = 0; j < 4; ++j) {
            const int n = n0 + wn * 64 + j * 16 + cn;
            const size_t base = (size_t)m * Ndim + n;
#pragma unroll
            for (int r = 0; r < 4; ++r)
                C[base + (size_t)r * Ndim] = acc[i][j][r] + bv[j];
        }
    }
}

// ---------------------------------------------------------------------------
// Kernel 2: LoRA read-modify-write, fp32, no scratch.
// Per 64-row block: P_q[row][r] = sum_d x[row,d]*Waq[r,d] (same for v), then
// out[row, n] += sum_r P_q[row][r]*Wbq[n,r] (n<D); v slice at n+2D.
// ---------------------------------------------------------------------------
__global__ __launch_bounds__(256) void lora_rmw(
    const float* __restrict__ x,     // M x 1024
    const float* __restrict__ Waq,   // 16 x 1024
    const float* __restrict__ Wbq,   // 1024 x 16
    const float* __restrict__ Wav,   // 16 x 1024
    const float* __restrict__ Wbv,   // 1024 x 16
    float* __restrict__ out)         // M x 3072
{
    __shared__ float Pq[64][16];
    __shared__ float Pv[64][16];
    const int t  = threadIdx.x;
    const int m0 = blockIdx.x * 64;

    // phase 1: thread t -> row t>>2, ranks (t&3)*4 .. +3 (both q and v)
    {
        const int row = t >> 2;
        const int r0  = (t & 3) * 4;
        float accq[4] = {0.f, 0.f, 0.f, 0.f};
        float accv[4] = {0.f, 0.f, 0.f, 0.f};
        const float* xr = x + (size_t)(m0 + row) * Kdim;
        for (int d = 0; d < Kdim; d += 4) {
            floatx4 xv = *(const floatx4*)(xr + d);
#pragma unroll
            for (int rr = 0; rr < 4; ++rr) {
                floatx4 wq = *(const floatx4*)(Waq + (size_t)(r0 + rr) * Kdim + d);
                floatx4 wv = *(const floatx4*)(Wav + (size_t)(r0 + rr) * Kdim + d);
#pragma unroll
                for (int e = 0; e < 4; ++e) {
                    accq[rr] += xv[e] * wq[e];
                    accv[rr] += xv[e] * wv[e];
                }
            }
        }
#pragma unroll
        for (int rr = 0; rr < 4; ++rr) {
            Pq[row][r0 + rr] = accq[rr];
            Pv[row][r0 + rr] = accv[rr];
        }
    }
    __syncthreads();

    // phase 2: 256 threads cover 2048 cols (1024 q + 1024 v), 8 each
    const int col  = t * 8;                    // 0..2047
    const bool isq = col < 1024;
    const int nn0  = isq ? col : col - 1024;   // row index into Wb
    const int n    = isq ? col : col + 1024;   // output column
    const float* Wb = isq ? Wbq : Wbv;

    for (int row = 0; row < 64; ++row) {
        const float* P = isq ? Pq[row] : Pv[row];
        const size_t off = (size_t)(m0 + row) * Ndim + n;
        floatx4 o0 = *(const floatx4*)(out + off);
        floatx4 o1 = *(const floatx4*)(out + off + 4);
#pragma unroll
        for (int i = 0; i < 8; ++i) {
            floatx4 w0 = *(const floatx4*)(Wb + (size_t)(nn0 + i) * 16);
            floatx4 w1 = *(const floatx4*)(Wb + (size_t)(nn0 + i) * 16 + 4);
            floatx4 w2 = *(const floatx4*)(Wb + (size_t)(nn0 + i) * 16 + 8);
            floatx4 w3 = *(const floatx4*)(Wb + (size_t)(nn0 + i) * 16 + 12);
            float s = 0.f;
#pragma unroll
            for (int r = 0; r < 4; ++r)
                s += P[r] * w0[r] + P[r + 4] * w1[r] + P[r + 8] * w2[r] + P[r + 12] * w3[r];
            if (i < 4) o0[i] += s; else o1[i - 4] += s;
        }
        *(floatx4*)(out + off)     = o0;
        *(floatx4*)(out + off + 4) = o1;
    }
}

extern "C" void kernel_launch(void* const* d_in, const int* in_sizes, int n_in,
                              void* d_out, int out_size, void* d_ws, size_t ws_size,
                              hipStream_t stream)
{
    (void)in_sizes; (void)n_in; (void)out_size; (void)d_ws; (void)ws_size;
    const float* x    = (const float*)d_in[0];
    const float* Wqkv = (const float*)d_in[1];
    const float* bqkv = (const float*)d_in[2];
    const float* Waq  = (const float*)d_in[3];
    const float* Wbq  = (const float*)d_in[4];
    const float* Wav  = (const float*)d_in[5];
    const float* Wbv  = (const float*)d_in[6];
    float* out = (float*)d_out;

    gemm_bias<<<(Mdim / 128) * (Ndim / 128), 256, 0, stream>>>(x, Wqkv, bqkv, out);
    lora_rmw<<<Mdim / 64, 256, 0, stream>>>(x, Waq, Wbq, Wav, Wbv, out);
}

// Round 4
// 381.125 us; speedup vs baseline: 1.8746x; 1.8746x over previous
//
#include <hip/hip_runtime.h>
#include <hip/hip_bf16.h>

typedef __bf16 bf16x4 __attribute__((ext_vector_type(4)));
typedef __bf16 bf16x8 __attribute__((ext_vector_type(8)));
typedef float floatx4 __attribute__((ext_vector_type(4)));

#define GLD16(gp, lp) __builtin_amdgcn_global_load_lds(                      \
    (const __attribute__((address_space(1))) void*)(gp),                     \
    (__attribute__((address_space(3))) void*)(lp), 16, 0, 0)

constexpr int Mdim = 16384;   // B*S
constexpr int Ndim = 3072;    // 3*D
constexpr int Kdim = 1024;    // D

static __device__ __forceinline__ bf16x8 cvt8(floatx4 lo, floatx4 hi) {
    bf16x8 r;
#pragma unroll
    for (int e = 0; e < 4; ++e) { r[e] = (__bf16)lo[e]; r[e + 4] = (__bf16)hi[e]; }
    return r;
}

// ===========================================================================
// FAST PATH (requires ws_size >= 40 MB)
// ===========================================================================

// --- prep 1: W_eff = W_qkv + LoRA fold, fp32 accumulate -> bf16 ------------
__global__ __launch_bounds__(256) void build_weff(
    const float* __restrict__ Wqkv,   // 3072 x 1024
    const float* __restrict__ Waq,    // 16 x 1024
    const float* __restrict__ Wbq,    // 1024 x 16
    const float* __restrict__ Wav,    // 16 x 1024
    const float* __restrict__ Wbv,    // 1024 x 16
    __hip_bfloat16* __restrict__ Weff)
{
    const int idx = (blockIdx.x * 256 + threadIdx.x) * 4;  // e*1024 + d
    const int e = idx >> 10;
    const int d = idx & 1023;
    floatx4 v = *(const floatx4*)(Wqkv + idx);
    if (e < 1024) {
#pragma unroll
        for (int r = 0; r < 16; ++r) {
            const float wb = Wbq[e * 16 + r];
            floatx4 wa = *(const floatx4*)(Waq + r * 1024 + d);
#pragma unroll
            for (int q = 0; q < 4; ++q) v[q] += wb * wa[q];
        }
    } else if (e >= 2048) {
        const int e2 = e - 2048;
#pragma unroll
        for (int r = 0; r < 16; ++r) {
            const float wb = Wbv[e2 * 16 + r];
            floatx4 wa = *(const floatx4*)(Wav + r * 1024 + d);
#pragma unroll
            for (int q = 0; q < 4; ++q) v[q] += wb * wa[q];
        }
    }
    bf16x4 o;
#pragma unroll
    for (int q = 0; q < 4; ++q) o[q] = (__bf16)v[q];
    *(bf16x4*)(Weff + idx) = o;
}

// --- prep 2: x fp32 -> bf16 -------------------------------------------------
__global__ __launch_bounds__(256) void cvt_x(
    const float* __restrict__ x, __hip_bfloat16* __restrict__ xb)
{
    const size_t idx = ((size_t)blockIdx.x * 256 + threadIdx.x) * 8;
    bf16x8 r = cvt8(*(const floatx4*)(x + idx), *(const floatx4*)(x + idx + 4));
    *(bf16x8*)(xb + idx) = r;
}

// --- main GEMM: C = A * Bw^T + bias.  bf16 in, fp32 out. m97 structure. ----
__global__ __launch_bounds__(256, 3) void gemm_bf16(
    const __hip_bfloat16* __restrict__ A,     // M x K bf16
    const __hip_bfloat16* __restrict__ Bw,    // N x K bf16 (W_eff)
    const float* __restrict__ bias,           // N fp32
    float* __restrict__ C)                    // M x N fp32
{
    constexpr int TK = 32;
    __shared__ __hip_bfloat16 As[128 * TK];   // no pad: global_load_lds layout
    __shared__ __hip_bfloat16 Bs[128 * TK];

    const int t    = threadIdx.x;
    const int wave = t >> 6;
    const int lane = t & 63;
    const int bx   = blockIdx.x % (Ndim / 128);   // 24 n-tiles
    const int by   = blockIdx.x / (Ndim / 128);
    const int m0   = by * 128;
    const int n0   = bx * 128;
    const int wm   = wave >> 1;                   // 2x2 wave grid, 64x64 each
    const int wn   = wave & 1;

    // staging: LDS byte addr = wave*1024 + lane*16  == (srow*TK+scol)*2
    const int srow = wave * 16 + (lane >> 2);
    const int scol = (lane & 3) * 8;

    const __hip_bfloat16* Ag0 = A  + (size_t)(m0 + srow) * Kdim + scol;
    const __hip_bfloat16* Ag1 = Ag0 + (size_t)64 * Kdim;
    const __hip_bfloat16* Bg0 = Bw + (size_t)(n0 + srow) * Kdim + scol;
    const __hip_bfloat16* Bg1 = Bg0 + (size_t)64 * Kdim;

    __hip_bfloat16* Al0 = &As[srow * TK + scol];
    __hip_bfloat16* Al1 = &As[(srow + 64) * TK + scol];
    __hip_bfloat16* Bl0 = &Bs[srow * TK + scol];
    __hip_bfloat16* Bl1 = &Bs[(srow + 64) * TK + scol];

    // MFMA A/B operand layout: free dim = lane&15, k = (lane>>4)*8 + j
    const int fm = lane & 15;
    const int fk = (lane >> 4) * 8;

    floatx4 acc[4][4];
#pragma unroll
    for (int i = 0; i < 4; ++i)
#pragma unroll
        for (int j = 0; j < 4; ++j)
            acc[i][j] = (floatx4){0.f, 0.f, 0.f, 0.f};

    for (int kt = 0; kt < Kdim; kt += TK) {
        GLD16(Ag0 + kt, Al0);
        GLD16(Ag1 + kt, Al1);
        GLD16(Bg0 + kt, Bl0);
        GLD16(Bg1 + kt, Bl1);
        __syncthreads();                 // drains vmcnt: staging visible

        bf16x8 af[4], bfr[4];
#pragma unroll
        for (int i = 0; i < 4; ++i) {
            af[i]  = *(const bf16x8*)&As[(wm * 64 + i * 16 + fm) * TK + fk];
            bfr[i] = *(const bf16x8*)&Bs[(wn * 64 + i * 16 + fm) * TK + fk];
        }
#pragma unroll
        for (int i = 0; i < 4; ++i)
#pragma unroll
            for (int j = 0; j < 4; ++j)
                acc[i][j] = __builtin_amdgcn_mfma_f32_16x16x32_bf16(af[i], bfr[j], acc[i][j], 0, 0, 0);
        __syncthreads();                 // LDS reads done before next stage
    }

    // epilogue: C/D layout col(n)=lane&15, row(m)=(lane>>4)*4 + reg
    const int cn = lane & 15;
    const int cm = (lane >> 4) * 4;
    float bv[4];
#pragma unroll
    for (int j = 0; j < 4; ++j)
        bv[j] = bias[n0 + wn * 64 + j * 16 + cn];

#pragma unroll
    for (int i = 0; i < 4; ++i) {
        const int m = m0 + wm * 64 + i * 16 + cm;
#pragma unroll
        for (int j = 0; j < 4; ++j) {
            const int n = n0 + wn * 64 + j * 16 + cn;
            const size_t base = (size_t)m * Ndim + n;
#pragma unroll
            for (int r = 0; r < 4; ++r)
                C[base + (size_t)r * Ndim] = acc[i][j][r] + bv[j];
        }
    }
}

// ===========================================================================
// FALLBACK PATH (R2, proven): used only if ws_size < 40 MB
// ===========================================================================

__global__ __launch_bounds__(256, 2) void gemm_bias_f32(
    const float* __restrict__ A, const float* __restrict__ Bw,
    const float* __restrict__ bias, float* __restrict__ C)
{
    constexpr int TK = 32;
    __shared__ __hip_bfloat16 As[128 * TK];
    __shared__ __hip_bfloat16 Bs[128 * TK];

    const int t    = threadIdx.x;
    const int wave = t >> 6;
    const int lane = t & 63;
    const int bx   = blockIdx.x % (Ndim / 128);
    const int by   = blockIdx.x / (Ndim / 128);
    const int m0   = by * 128;
    const int n0   = bx * 128;
    const int wm   = wave >> 1;
    const int wn   = wave & 1;
    const int srow = wave * 16 + (lane >> 2);
    const int scol = (lane & 3) * 8;

    const float* Ag0 = A  + (size_t)(m0 + srow) * Kdim + scol;
    const float* Ag1 = Ag0 + (size_t)64 * Kdim;
    const float* Bg0 = Bw + (size_t)(n0 + srow) * Kdim + scol;
    const float* Bg1 = Bg0 + (size_t)64 * Kdim;

    __hip_bfloat16* Al0 = &As[srow * TK + scol];
    __hip_bfloat16* Al1 = &As[(srow + 64) * TK + scol];
    __hip_bfloat16* Bl0 = &Bs[srow * TK + scol];
    __hip_bfloat16* Bl1 = &Bs[(srow + 64) * TK + scol];

    const int fm = lane & 15;
    const int fk = (lane >> 4) * 8;

    floatx4 acc[4][4];
#pragma unroll
    for (int i = 0; i < 4; ++i)
#pragma unroll
        for (int j = 0; j < 4; ++j)
            acc[i][j] = (floatx4){0.f, 0.f, 0.f, 0.f};

    for (int kt = 0; kt < Kdim; kt += TK) {
        bf16x8 a0 = cvt8(*(const floatx4*)(Ag0 + kt), *(const floatx4*)(Ag0 + kt + 4));
        bf16x8 a1 = cvt8(*(const floatx4*)(Ag1 + kt), *(const floatx4*)(Ag1 + kt + 4));
        bf16x8 b0 = cvt8(*(const floatx4*)(Bg0 + kt), *(const floatx4*)(Bg0 + kt + 4));
        bf16x8 b1 = cvt8(*(const floatx4*)(Bg1 + kt), *(const floatx4*)(Bg1 + kt + 4));
        __syncthreads();
        *(bf16x8*)Al0 = a0;
        *(bf16x8*)Al1 = a1;
        *(bf16x8*)Bl0 = b0;
        *(bf16x8*)Bl1 = b1;
        __syncthreads();

        bf16x8 af[4], bfr[4];
#pragma unroll
        for (int i = 0; i < 4; ++i) {
            af[i]  = *(const bf16x8*)&As[(wm * 64 + i * 16 + fm) * TK + fk];
            bfr[i] = *(const bf16x8*)&Bs[(wn * 64 + i * 16 + fm) * TK + fk];
        }
#pragma unroll
        for (int i = 0; i < 4; ++i)
#pragma unroll
            for (int j = 0; j < 4; ++j)
                acc[i][j] = __builtin_amdgcn_mfma_f32_16x16x32_bf16(af[i], bfr[j], acc[i][j], 0, 0, 0);
    }

    const int cn = lane & 15;
    const int cm = (lane >> 4) * 4;
    float bv[4];
#pragma unroll
    for (int j = 0; j < 4; ++j)
        bv[j] = bias[n0 + wn * 64 + j * 16 + cn];
#pragma unroll
    for (int i = 0; i < 4; ++i) {
        const int m = m0 + wm * 64 + i * 16 + cm;
#pragma unroll
        for (int j = 0; j < 4; ++j) {
            const int n = n0 + wn * 64 + j * 16 + cn;
            const size_t base = (size_t)m * Ndim + n;
#pragma unroll
            for (int r = 0; r < 4; ++r)
                C[base + (size_t)r * Ndim] = acc[i][j][r] + bv[j];
        }
    }
}

__global__ __launch_bounds__(256) void lora_rmw(
    const float* __restrict__ x,
    const float* __restrict__ Waq, const float* __restrict__ Wbq,
    const float* __restrict__ Wav, const float* __restrict__ Wbv,
    float* __restrict__ out)
{
    __shared__ float Pq[64][16];
    __shared__ float Pv[64][16];
    const int t  = threadIdx.x;
    const int m0 = blockIdx.x * 64;
    {
        const int row = t >> 2;
        const int r0  = (t & 3) * 4;
        float accq[4] = {0.f, 0.f, 0.f, 0.f};
        float accv[4] = {0.f, 0.f, 0.f, 0.f};
        const float* xr = x + (size_t)(m0 + row) * Kdim;
        for (int d = 0; d < Kdim; d += 4) {
            floatx4 xv = *(const floatx4*)(xr + d);
#pragma unroll
            for (int rr = 0; rr < 4; ++rr) {
                floatx4 wq = *(const floatx4*)(Waq + (size_t)(r0 + rr) * Kdim + d);
                floatx4 wv = *(const floatx4*)(Wav + (size_t)(r0 + rr) * Kdim + d);
#pragma unroll
                for (int e = 0; e < 4; ++e) {
                    accq[rr] += xv[e] * wq[e];
                    accv[rr] += xv[e] * wv[e];
                }
            }
        }
#pragma unroll
        for (int rr = 0; rr < 4; ++rr) {
            Pq[row][r0 + rr] = accq[rr];
            Pv[row][r0 + rr] = accv[rr];
        }
    }
    __syncthreads();
    const int col  = t * 8;
    const bool isq = col < 1024;
    const int nn0  = isq ? col : col - 1024;
    const int n    = isq ? col : col + 1024;
    const float* Wb = isq ? Wbq : Wbv;
    for (int row = 0; row < 64; ++row) {
        const float* P = isq ? Pq[row] : Pv[row];
        const size_t off = (size_t)(m0 + row) * Ndim + n;
        floatx4 o0 = *(const floatx4*)(out + off);
        floatx4 o1 = *(const floatx4*)(out + off + 4);
#pragma unroll
        for (int i = 0; i < 8; ++i) {
            floatx4 w0 = *(const floatx4*)(Wb + (size_t)(nn0 + i) * 16);
            floatx4 w1 = *(const floatx4*)(Wb + (size_t)(nn0 + i) * 16 + 4);
            floatx4 w2 = *(const floatx4*)(Wb + (size_t)(nn0 + i) * 16 + 8);
            floatx4 w3 = *(const floatx4*)(Wb + (size_t)(nn0 + i) * 16 + 12);
            float s = 0.f;
#pragma unroll
            for (int r = 0; r < 4; ++r)
                s += P[r] * w0[r] + P[r + 4] * w1[r] + P[r + 8] * w2[r] + P[r + 12] * w3[r];
            if (i < 4) o0[i] += s; else o1[i - 4] += s;
        }
        *(floatx4*)(out + off)     = o0;
        *(floatx4*)(out + off + 4) = o1;
    }
}

extern "C" void kernel_launch(void* const* d_in, const int* in_sizes, int n_in,
                              void* d_out, int out_size, void* d_ws, size_t ws_size,
                              hipStream_t stream)
{
    (void)in_sizes; (void)n_in; (void)out_size;
    const float* x    = (const float*)d_in[0];
    const float* Wqkv = (const float*)d_in[1];
    const float* bqkv = (const float*)d_in[2];
    const float* Waq  = (const float*)d_in[3];
    const float* Wbq  = (const float*)d_in[4];
    const float* Wav  = (const float*)d_in[5];
    const float* Wbv  = (const float*)d_in[6];
    float* out = (float*)d_out;

    const size_t WEFF_BYTES = (size_t)Ndim * Kdim * sizeof(__hip_bfloat16); // 6.3 MB
    const size_t XB_BYTES   = (size_t)Mdim * Kdim * sizeof(__hip_bfloat16); // 33.5 MB

    if (ws_size >= WEFF_BYTES + XB_BYTES) {
        // fast path: fold LoRA into bf16 W_eff, bf16 x, single MFMA GEMM
        __hip_bfloat16* Weff = (__hip_bfloat16*)d_ws;
        __hip_bfloat16* xb   = (__hip_bfloat16*)((char*)d_ws + WEFF_BYTES);
        build_weff<<<(Ndim * Kdim / 4) / 256, 256, 0, stream>>>(Wqkv, Waq, Wbq, Wav, Wbv, Weff);
        cvt_x<<<(int)(((size_t)Mdim * Kdim / 8) / 256), 256, 0, stream>>>(x, xb);
        gemm_bf16<<<(Mdim / 128) * (Ndim / 128), 256, 0, stream>>>(xb, Weff, bqkv, out);
    } else {
        // fallback: R2 proven path (no scratch)
        gemm_bias_f32<<<(Mdim / 128) * (Ndim / 128), 256, 0, stream>>>(x, Wqkv, bqkv, out);
        lora_rmw<<<Mdim / 64, 256, 0, stream>>>(x, Waq, Wbq, Wav, Wbv, out);
    }
}